// Round 9
// baseline (17315.506 us; speedup 1.0000x reference)
//
#include <hip/hip_runtime.h>
#include <math.h>

#define DD 64
#define NSWEEP 8

__device__ __forceinline__ float rdlane(float v, int l) {
    return __int_as_float(__builtin_amdgcn_readlane(__float_as_int(v), l));
}
__device__ __forceinline__ float bperm(int paddr, float v) {
    return __int_as_float(__builtin_amdgcn_ds_bpermute(paddr, __float_as_int(v)));
}

// Cholesky (Xs = L L^T) + one-sided Jacobi on columns of L, register-resident.
// 4 waves per block, one matrix per wave; the 16.6KB epilogue LDS buffer is
// time-shared across the 4 waves so LDS/matrix is 4x smaller -> occupancy is
// VGPR-capped (16 waves/CU) instead of LDS-capped (8).
__global__ __launch_bounds__(256, 4)
void logeig_chol1s_kernel(const float* __restrict__ X, float* __restrict__ out, int nb) {
    __shared__ float M[DD][DD + 1];   // epilogue buffer, time-shared by the 4 waves

    const int tid  = threadIdx.x;
    const int lane = tid & 63;
    const int w4   = tid >> 6;        // wave id 0..3
    int mb = blockIdx.x * 4 + w4;
    if (mb >= nb) mb = nb - 1;        // clamp (barrier-safe; nb%4==0 in practice)

    const float* Xb = X + (size_t)mb * DD * DD;
    float* Ob = out + (size_t)mb * DD * DD;

    // w = column `lane` of Xs = 0.5*(X + X^T), read directly from global:
    // X[e][lane] coalesced; X[lane][e] scattered (L2-resident after the first).
    float w[DD];
    #pragma unroll
    for (int e = 0; e < DD; ++e)
        w[e] = 0.5f * (Xb[e * DD + lane] + Xb[lane * DD + e]);

    // ---- In-wave right-looking Cholesky: lane j ends owning column j of L ----
    #pragma unroll
    for (int k = 0; k < DD; ++k) {
        const float pivot = rdlane(w[k], k);          // A'[k][k] > 0 (SPD)
        const float rinv  = 1.0f / sqrtf(pivot);
        const float ljk   = w[k] * rinv;              // L[lane][k], valid lane >= k
        const bool  gtk   = (lane > k);
        const bool  eqk   = (lane == k);
        #pragma unroll
        for (int e = k; e < DD; ++e) {
            const float lek = rdlane(w[e], k) * rinv; // L[e][k] (uniform)
            const float upd = fmaf(-lek, ljk, w[e]);
            w[e] = eqk ? lek : (gtk ? upd : w[e]);
        }
    }
    // Zero strict upper part
    #pragma unroll
    for (int e = 0; e < DD - 1; ++e)
        w[e] = (e < lane) ? 0.0f : w[e];

    // Initial column norm^2 (maintained incrementally)
    float nown;
    {
        float n0 = 0.f, n1 = 0.f;
        #pragma unroll
        for (int e = 0; e < DD; e += 2) {
            n0 = fmaf(w[e],     w[e],     n0);
            n1 = fmaf(w[e + 1], w[e + 1], n1);
        }
        nown = n0 + n1;
    }

    const int lane4 = lane << 2;

    for (int sw = 0; sw < NSWEEP; ++sw) {
        bool sweep_rotated = false;
        for (int m = 1; m < DD; ++m) {
            const int paddr = lane4 ^ (m << 2);   // partner*4 (XOR pairing)

            float oth[DD];
            #pragma unroll
            for (int e = 0; e < DD; ++e) oth[e] = bperm(paddr, w[e]);

            // d = w . oth (identical summation order both lanes -> bitwise-equal)
            float d0 = 0.f, d1 = 0.f;
            #pragma unroll
            for (int e = 0; e < DD; e += 2) {
                d0 = fmaf(w[e],     oth[e],     d0);
                d1 = fmaf(w[e + 1], oth[e + 1], d1);
            }
            const float d    = d0 + d1;
            const float noth = bperm(paddr, nown);

            // Relative threshold 1e-6: skipped rotations perturb the output
            // ~1e-6*log-scale << fp32 floor; lets late sweeps become no-ops.
            const bool dorot = (d * d > 1e-12f * nown * noth);
            if (__any(dorot)) {
                sweep_rotated = true;
                const bool  islo = (paddr > lane4);   // low lane plays p
                const float app  = islo ? nown : noth;
                const float aqq  = islo ? noth : nown;
                float tau = (aqq - app) * 0.5f / d;
                float t   = 1.0f / (fabsf(tau) + sqrtf(fmaf(tau, tau, 1.0f)));
                t = copysignf(t, tau);
                float c = 1.0f / sqrtf(fmaf(t, t, 1.0f));
                float s = t * c;
                float tsgn = islo ? -t : t;           // nown' = nown -+ t*d
                if (!islo) s = -s;
                if (!dorot) { c = 1.0f; s = 0.0f; tsgn = 0.0f; }
                nown = fmaf(tsgn, d, nown);
                #pragma unroll
                for (int e = 0; e < DD; ++e)
                    w[e] = fmaf(-s, oth[e], c * w[e]);
            }
        }
        // A sweep with zero rotations is identity -> all later sweeps identity.
        if (!sweep_rotated) break;
    }

    // lambda_j = ||w_j||^2 (recomputed fresh)
    float nf0 = 0.f, nf1 = 0.f;
    #pragma unroll
    for (int e = 0; e < DD; e += 2) {
        nf0 = fmaf(w[e],     w[e],     nf0);
        nf1 = fmaf(w[e + 1], w[e + 1], nf1);
    }
    const float nn  = nf0 + nf1;                      // = lambda_j
    const float scl = logf(fmaxf(nn, 1e-7f)) / nn;    // log(clip(lam))/lam

    // Epilogue: out[r][c] = sum_j W[r][j] * scl_j * W[c][j]
    // Time-share the single LDS buffer across the 4 waves.
    for (int wr = 0; wr < 4; ++wr) {
        if (w4 == wr) {
            #pragma unroll
            for (int e = 0; e < DD; ++e) M[e][lane] = w[e];
        }
        __syncthreads();
        if (w4 == wr) {
            float vrow[DD];
            #pragma unroll
            for (int j = 0; j < DD; ++j) vrow[j] = M[lane][j] * rdlane(scl, j);

            #pragma unroll 4
            for (int r = 0; r < DD; ++r) {
                float a0 = 0.f, a1 = 0.f;
                #pragma unroll
                for (int j = 0; j < DD; j += 2) {
                    a0 = fmaf(M[r][j],     vrow[j],     a0);
                    a1 = fmaf(M[r][j + 1], vrow[j + 1], a1);
                }
                Ob[r * DD + lane] = a0 + a1;
            }
        }
        __syncthreads();
    }
}

extern "C" void kernel_launch(void* const* d_in, const int* in_sizes, int n_in,
                              void* d_out, int out_size, void* d_ws, size_t ws_size,
                              hipStream_t stream) {
    (void)n_in; (void)d_ws; (void)ws_size; (void)out_size;
    const float* X = (const float*)d_in[0];
    float* out = (float*)d_out;
    int nb = in_sizes[0] / (DD * DD);
    dim3 grid((nb + 3) / 4);
    dim3 block(256);
    hipLaunchKernelGGL(logeig_chol1s_kernel, grid, block, 0, stream, X, out, nb);
}

// Round 10
// 6495.558 us; speedup vs baseline: 2.6657x; 2.6657x over previous
//
#include <hip/hip_runtime.h>
#include <math.h>

#define DD 64
#define NSWEEP 8

__device__ __forceinline__ float rdlane(float v, int l) {
    return __int_as_float(__builtin_amdgcn_readlane(__float_as_int(v), l));
}
__device__ __forceinline__ float bperm(int paddr, float v) {
    return __int_as_float(__builtin_amdgcn_ds_bpermute(paddr, __float_as_int(v)));
}

// Cholesky (Xs = L L^T) + one-sided Jacobi on columns of L, register-resident.
// 4 waves per block, one matrix per wave; the single 16.6KB LDS buffer is
// time-shared (prologue transpose + epilogue) so LDS/matrix is 4x smaller and
// occupancy is VGPR-capped (~16 waves/CU) instead of LDS-capped (8).
// launch_bounds(256,2): VGPR cap 256 -> allocator uses its ~80-reg pattern,
// NO scratch spill (round-9 lesson: (256,4) caps at 128 and spills 54GB).
__global__ __launch_bounds__(256, 2)
void logeig_chol1s_kernel(const float* __restrict__ X, float* __restrict__ out, int nb) {
    __shared__ float M[DD][DD + 1];   // time-shared staging/epilogue buffer

    const int tid  = threadIdx.x;
    const int lane = tid & 63;
    const int w4   = tid >> 6;        // wave id 0..3
    int mb = blockIdx.x * 4 + w4;
    if (mb >= nb) mb = nb - 1;        // duplicate-work clamp (barrier-uniform)

    const float* Xb = X + (size_t)mb * DD * DD;
    float* Ob = out + (size_t)mb * DD * DD;

    // ---- Prologue: symmetrize via time-shared LDS transpose ----
    // w = column `lane` of Xs = 0.5*(X + X^T). Coalesced loads only; bounded
    // register pressure (round-9's direct scattered reads pushed past the cap).
    float w[DD];
    for (int wr = 0; wr < 4; ++wr) {
        if (w4 == wr) {
            #pragma unroll
            for (int e = 0; e < DD; ++e) M[e][lane] = Xb[e * DD + lane];
        }
        __syncthreads();
        if (w4 == wr) {
            #pragma unroll
            for (int e = 0; e < DD; ++e) w[e] = 0.5f * (M[e][lane] + M[lane][e]);
        }
        __syncthreads();
    }

    // ---- In-wave right-looking Cholesky: lane j ends owning column j of L ----
    #pragma unroll
    for (int k = 0; k < DD; ++k) {
        const float pivot = rdlane(w[k], k);          // A'[k][k] > 0 (SPD)
        const float rinv  = 1.0f / sqrtf(pivot);
        const float ljk   = w[k] * rinv;              // L[lane][k], valid lane >= k
        const bool  gtk   = (lane > k);
        const bool  eqk   = (lane == k);
        #pragma unroll
        for (int e = k; e < DD; ++e) {
            const float lek = rdlane(w[e], k) * rinv; // L[e][k] (uniform)
            const float upd = fmaf(-lek, ljk, w[e]);
            w[e] = eqk ? lek : (gtk ? upd : w[e]);
        }
    }
    // Zero strict upper part
    #pragma unroll
    for (int e = 0; e < DD - 1; ++e)
        w[e] = (e < lane) ? 0.0f : w[e];

    // Initial column norm^2 (maintained incrementally)
    float nown;
    {
        float n0 = 0.f, n1 = 0.f;
        #pragma unroll
        for (int e = 0; e < DD; e += 2) {
            n0 = fmaf(w[e],     w[e],     n0);
            n1 = fmaf(w[e + 1], w[e + 1], n1);
        }
        nown = n0 + n1;
    }

    const int lane4 = lane << 2;

    for (int sw = 0; sw < NSWEEP; ++sw) {
        bool sweep_rotated = false;
        for (int m = 1; m < DD; ++m) {
            const int paddr = lane4 ^ (m << 2);   // partner*4 (XOR pairing)

            float oth[DD];
            #pragma unroll
            for (int e = 0; e < DD; ++e) oth[e] = bperm(paddr, w[e]);

            // d = w . oth (identical summation order both lanes -> bitwise-equal)
            float d0 = 0.f, d1 = 0.f;
            #pragma unroll
            for (int e = 0; e < DD; e += 2) {
                d0 = fmaf(w[e],     oth[e],     d0);
                d1 = fmaf(w[e + 1], oth[e + 1], d1);
            }
            const float d    = d0 + d1;
            const float noth = bperm(paddr, nown);

            // Relative threshold 1e-6 (proven absmax-neutral in round 9):
            // lets late sweeps become all-skip so the early exit fires.
            const bool dorot = (d * d > 1e-12f * nown * noth);
            if (__any(dorot)) {
                sweep_rotated = true;
                const bool  islo = (paddr > lane4);   // low lane plays p
                const float app  = islo ? nown : noth;
                const float aqq  = islo ? noth : nown;
                float tau = (aqq - app) * 0.5f / d;
                float t   = 1.0f / (fabsf(tau) + sqrtf(fmaf(tau, tau, 1.0f)));
                t = copysignf(t, tau);
                float c = 1.0f / sqrtf(fmaf(t, t, 1.0f));
                float s = t * c;
                float tsgn = islo ? -t : t;           // nown' = nown -+ t*d
                if (!islo) s = -s;
                if (!dorot) { c = 1.0f; s = 0.0f; tsgn = 0.0f; }
                nown = fmaf(tsgn, d, nown);
                #pragma unroll
                for (int e = 0; e < DD; ++e)
                    w[e] = fmaf(-s, oth[e], c * w[e]);
            }
        }
        // Zero-rotation sweep == identity -> all later sweeps identity.
        if (!sweep_rotated) break;
    }

    // lambda_j = ||w_j||^2 (recomputed fresh)
    float nf0 = 0.f, nf1 = 0.f;
    #pragma unroll
    for (int e = 0; e < DD; e += 2) {
        nf0 = fmaf(w[e],     w[e],     nf0);
        nf1 = fmaf(w[e + 1], w[e + 1], nf1);
    }
    const float nn  = nf0 + nf1;                      // = lambda_j
    const float scl = logf(fmaxf(nn, 1e-7f)) / nn;    // log(clip(lam))/lam

    // ---- Epilogue: out[r][c] = sum_j W[r][j] * scl_j * W[c][j] ----
    // Time-share the single LDS buffer across the 4 waves.
    for (int wr = 0; wr < 4; ++wr) {
        if (w4 == wr) {
            #pragma unroll
            for (int e = 0; e < DD; ++e) M[e][lane] = w[e];
        }
        __syncthreads();
        if (w4 == wr) {
            float vrow[DD];
            #pragma unroll
            for (int j = 0; j < DD; ++j) vrow[j] = M[lane][j] * rdlane(scl, j);

            #pragma unroll 4
            for (int r = 0; r < DD; ++r) {
                float a0 = 0.f, a1 = 0.f;
                #pragma unroll
                for (int j = 0; j < DD; j += 2) {
                    a0 = fmaf(M[r][j],     vrow[j],     a0);
                    a1 = fmaf(M[r][j + 1], vrow[j + 1], a1);
                }
                Ob[r * DD + lane] = a0 + a1;
            }
        }
        __syncthreads();
    }
}

extern "C" void kernel_launch(void* const* d_in, const int* in_sizes, int n_in,
                              void* d_out, int out_size, void* d_ws, size_t ws_size,
                              hipStream_t stream) {
    (void)n_in; (void)d_ws; (void)ws_size; (void)out_size;
    const float* X = (const float*)d_in[0];
    float* out = (float*)d_out;
    int nb = in_sizes[0] / (DD * DD);
    dim3 grid((nb + 3) / 4);
    dim3 block(256);
    hipLaunchKernelGGL(logeig_chol1s_kernel, grid, block, 0, stream, X, out, nb);
}

// Round 11
// 5460.033 us; speedup vs baseline: 3.1713x; 1.1897x over previous
//
#include <hip/hip_runtime.h>
#include <math.h>

#define DD 64
#define NSWEEP 8

__device__ __forceinline__ float rdlane(float v, int l) {
    return __int_as_float(__builtin_amdgcn_readlane(__float_as_int(v), l));
}
__device__ __forceinline__ float bperm(int paddr, float v) {
    return __int_as_float(__builtin_amdgcn_ds_bpermute(paddr, __float_as_int(v)));
}

// ---------------- Kernel 1: Cholesky + one-sided Jacobi sweeps ----------------
// 64-thread blocks, ZERO LDS -> occupancy is register-capped (~12 waves/CU),
// not LDS-capped (8) as in rounds 7/8/10. Writes W columns into d_out (stash).
__global__ __launch_bounds__(64, 3)
void logeig_sweeps_kernel(const float* __restrict__ X, float* __restrict__ Wout, int nb) {
    const int b = blockIdx.x;
    if (b >= nb) return;
    const int lane = threadIdx.x & 63;
    const float* Xb = X + (size_t)b * DD * DD;

    // Symmetrize directly from global: coalesced column + row (L1/L2-served).
    float w[DD];
    #pragma unroll
    for (int e = 0; e < DD; ++e)
        w[e] = 0.5f * (Xb[e * DD + lane] + Xb[lane * DD + e]);

    // ---- In-wave right-looking Cholesky: lane j ends owning column j of L ----
    #pragma unroll
    for (int k = 0; k < DD; ++k) {
        const float pivot = rdlane(w[k], k);          // A'[k][k] > 0 (SPD)
        const float rinv  = 1.0f / sqrtf(pivot);
        const float ljk   = w[k] * rinv;              // L[lane][k], valid lane >= k
        const bool  gtk   = (lane > k);
        const bool  eqk   = (lane == k);
        #pragma unroll
        for (int e = k; e < DD; ++e) {
            const float lek = rdlane(w[e], k) * rinv; // L[e][k] (uniform)
            const float upd = fmaf(-lek, ljk, w[e]);
            w[e] = eqk ? lek : (gtk ? upd : w[e]);
        }
    }
    #pragma unroll
    for (int e = 0; e < DD - 1; ++e)
        w[e] = (e < lane) ? 0.0f : w[e];

    // Initial column norm^2 (maintained incrementally)
    float nown;
    {
        float n0 = 0.f, n1 = 0.f;
        #pragma unroll
        for (int e = 0; e < DD; e += 2) {
            n0 = fmaf(w[e],     w[e],     n0);
            n1 = fmaf(w[e + 1], w[e + 1], n1);
        }
        nown = n0 + n1;
    }

    const int lane4 = lane << 2;

    for (int sw = 0; sw < NSWEEP; ++sw) {
        bool sweep_rotated = false;
        for (int m = 1; m < DD; ++m) {
            const int paddr = lane4 ^ (m << 2);   // partner*4 (XOR pairing)

            // One bpermute per element; asm pin forbids rematerialization
            // (round-8 evidence: pinned values park in AGPRs - cheap VALU
            // moves on the unified file, not re-issued DS ops).
            float oth[DD];
            #pragma unroll
            for (int e = 0; e < DD; ++e) oth[e] = bperm(paddr, w[e]);
            #pragma unroll
            for (int e = 0; e < DD; ++e) asm volatile("" : "+v"(oth[e]));

            // d = w . oth (identical summation order both lanes -> bitwise-equal)
            float d0 = 0.f, d1 = 0.f, d2 = 0.f, d3 = 0.f;
            #pragma unroll
            for (int e = 0; e < DD; e += 4) {
                d0 = fmaf(w[e],     oth[e],     d0);
                d1 = fmaf(w[e + 1], oth[e + 1], d1);
                d2 = fmaf(w[e + 2], oth[e + 2], d2);
                d3 = fmaf(w[e + 3], oth[e + 3], d3);
            }
            const float d    = (d0 + d1) + (d2 + d3);
            const float noth = bperm(paddr, nown);

            // Relative threshold 1e-5: skipped rotations perturb the output
            // ~1e-5 * log-scale << 6.6e-2 threshold; late sweeps all-skip.
            const bool dorot = (d * d > 1e-10f * nown * noth);
            if (__any(dorot)) {
                sweep_rotated = true;
                const bool  islo = (paddr > lane4);   // low lane plays p
                const float app  = islo ? nown : noth;
                const float aqq  = islo ? noth : nown;
                float tau = (aqq - app) * 0.5f / d;
                float t   = 1.0f / (fabsf(tau) + sqrtf(fmaf(tau, tau, 1.0f)));
                t = copysignf(t, tau);
                float c = 1.0f / sqrtf(fmaf(t, t, 1.0f));
                float s = t * c;
                float tsgn = islo ? -t : t;           // nown' = nown -+ t*d
                if (!islo) s = -s;
                if (!dorot) { c = 1.0f; s = 0.0f; tsgn = 0.0f; }
                nown = fmaf(tsgn, d, nown);
                #pragma unroll
                for (int e = 0; e < DD; ++e)
                    w[e] = fmaf(-s, oth[e], c * w[e]);
            }
        }
        if (!sweep_rotated) break;   // identity sweep -> all later identity
    }

    // Stash W (column per lane) into d_out; epilogue kernel transforms in place.
    float* Wb = Wout + (size_t)b * DD * DD;
    #pragma unroll
    for (int e = 0; e < DD; ++e)
        Wb[e * DD + lane] = w[e];    // coalesced
}

// ---------------- Kernel 2: epilogue out = W diag(scl) W^T (in place) --------
// One 256-thread block per matrix; W staged fully into LDS before any write,
// so the in-place overwrite of d_out is race-free (block-local).
__global__ __launch_bounds__(256, 2)
void logeig_epilogue_kernel(float* __restrict__ out, int nb) {
    __shared__ float M[DD][DD + 1];
    __shared__ float sc[DD];

    const int b = blockIdx.x;
    if (b >= nb) return;
    const int tid  = threadIdx.x;
    const int lane = tid & 63;
    const int w4   = tid >> 6;
    float* Ob = out + (size_t)b * DD * DD;

    #pragma unroll
    for (int ii = 0; ii < 16; ++ii) {
        int r = w4 * 16 + ii;
        M[r][lane] = Ob[r * DD + lane];
    }
    __syncthreads();

    if (tid < DD) {
        float n0 = 0.f, n1 = 0.f;
        #pragma unroll
        for (int e = 0; e < DD; e += 2) {
            n0 = fmaf(M[e][tid],     M[e][tid],     n0);
            n1 = fmaf(M[e + 1][tid], M[e + 1][tid], n1);
        }
        const float nn = n0 + n1;                    // lambda_j
        sc[tid] = logf(fmaxf(nn, 1e-7f)) / nn;       // log(clip(lam))/lam
    }
    __syncthreads();

    float vrow[DD];
    #pragma unroll
    for (int j = 0; j < DD; ++j) vrow[j] = M[lane][j] * sc[j];

    float acc[16];
    #pragma unroll
    for (int ii = 0; ii < 16; ++ii) acc[ii] = 0.0f;

    for (int k = 0; k < DD; ++k) {
        const float vl = vrow[k];
        #pragma unroll
        for (int ii = 0; ii < 16; ++ii)
            acc[ii] = fmaf(M[w4 * 16 + ii][k], vl, acc[ii]);   // broadcast reads
    }

    __syncthreads();   // all reads of W done before overwriting
    #pragma unroll
    for (int ii = 0; ii < 16; ++ii)
        Ob[(size_t)(w4 * 16 + ii) * DD + lane] = acc[ii];
}

extern "C" void kernel_launch(void* const* d_in, const int* in_sizes, int n_in,
                              void* d_out, int out_size, void* d_ws, size_t ws_size,
                              hipStream_t stream) {
    (void)n_in; (void)d_ws; (void)ws_size; (void)out_size;
    const float* X = (const float*)d_in[0];
    float* out = (float*)d_out;
    int nb = in_sizes[0] / (DD * DD);
    hipLaunchKernelGGL(logeig_sweeps_kernel, dim3(nb), dim3(DD), 0, stream, X, out, nb);
    hipLaunchKernelGGL(logeig_epilogue_kernel, dim3(nb), dim3(256), 0, stream, out, nb);
}